// Round 6
// baseline (148.261 us; speedup 1.0000x reference)
//
#include <hip/hip_runtime.h>

#define TOKENS 8192
#define EXPERTS 64
#define HIDDEN 4096
#define SPLIT 8                  // K-split waves per block
#define KW (HIDDEN / SPLIT)      // 512 k per wave
#define NCHUNK (KW / 32)         // 16 chunks of K=32

typedef __attribute__((ext_vector_type(8))) short bf16x8;
typedef __attribute__((ext_vector_type(4))) float f32x4;

// round-to-nearest-even f32 -> bf16 bits
__device__ __forceinline__ unsigned short bf16_rne(float f) {
    unsigned u = __float_as_uint(f);
    unsigned r = (u + 0x7FFFu + ((u >> 16) & 1u)) >> 16;
    return (unsigned short)r;
}

// ---------------------------------------------------------------------------
// Kernel A: split w (f32) into hi/lo bf16 planes (RNE both), row-major [e][k]
// ---------------------------------------------------------------------------
__global__ void prep_w(const float* __restrict__ w,
                       unsigned short* __restrict__ wh,
                       unsigned short* __restrict__ wl) {
    const int i = blockIdx.x * 256 + threadIdx.x;   // 64*4096 elems
    const float f = w[i];
    const unsigned short hb = bf16_rne(f);
    const float hf = __uint_as_float(((unsigned)hb) << 16);
    wh[i] = hb;
    wl[i] = bf16_rne(f - hf);
}

// ---------------------------------------------------------------------------
// in-reg split of 8 x f32 -> hi (RNE) + lo (trunc) bf16x8
// ---------------------------------------------------------------------------
__device__ __forceinline__ void split8(const float4& f0, const float4& f1,
                                       bf16x8& h, bf16x8& l) {
    float fv[8] = {f0.x, f0.y, f0.z, f0.w, f1.x, f1.y, f1.z, f1.w};
#pragma unroll
    for (int j = 0; j < 8; ++j) {
        const unsigned u = __float_as_uint(fv[j]);
        const unsigned hb = (u + 0x7FFFu + ((u >> 16) & 1u)) >> 16;
        const float hf = __uint_as_float(hb << 16);
        const float lf = fv[j] - hf;                 // exact residual
        h[j] = (short)hb;
        l[j] = (short)(__float_as_uint(lf) >> 16);   // truncate lo
    }
}

__device__ __forceinline__ void do_chunk(const float4& a0, const float4& a1,
                                         const unsigned short* __restrict__ bh,
                                         const unsigned short* __restrict__ bl,
                                         int koff, f32x4 (&acc)[4]) {
    uint4 Bh[4], Bl[4];
#pragma unroll
    for (int n = 0; n < 4; ++n) {
        Bh[n] = *(const uint4*)(bh + (size_t)n * 16 * HIDDEN + koff);
        Bl[n] = *(const uint4*)(bl + (size_t)n * 16 * HIDDEN + koff);
    }
    bf16x8 ah, al;
    split8(a0, a1, ah, al);
#pragma unroll
    for (int n = 0; n < 4; ++n) {
        const bf16x8 bhv = *(const bf16x8*)&Bh[n];
        const bf16x8 blv = *(const bf16x8*)&Bl[n];
        acc[n] = __builtin_amdgcn_mfma_f32_16x16x32_bf16(ah, bhv, acc[n], 0, 0, 0);
        acc[n] = __builtin_amdgcn_mfma_f32_16x16x32_bf16(ah, blv, acc[n], 0, 0, 0);
        acc[n] = __builtin_amdgcn_mfma_f32_16x16x32_bf16(al, bhv, acc[n], 0, 0, 0);
    }
}

// ---------------------------------------------------------------------------
// Main fused kernel: 512 blocks x 512 threads. 16 tokens/block, 8 waves
// splitting K (512 each). Per wave: 1 M-frag x 4 N-frags of 16x16x32.
// LDS reduce across 8 waves, then softmax + top-9 + rescue-flag + outputs.
// ---------------------------------------------------------------------------
__global__ __launch_bounds__(512, 4)
void router_main(const float* __restrict__ x,
                 const unsigned short* __restrict__ whb,
                 const unsigned short* __restrict__ wlb,
                 float* __restrict__ out,
                 int* __restrict__ flag_cnt,
                 int* __restrict__ flag_list) {
    __shared__ float lds[SPLIT][16][66];  // 33.8 KB
    const int tid = threadIdx.x;
    const int w = tid >> 6;               // 0..7: K-split id
    const int lane = tid & 63;
    const int g = lane >> 4;              // k-octet (A) / k-octet (B)
    const int c = lane & 15;              // token row (A) / expert col (B)
    const int t0 = blockIdx.x * 16;
    const int k0 = w * KW;

    f32x4 acc[4];
#pragma unroll
    for (int n = 0; n < 4; ++n) acc[n] = (f32x4)0.0f;

    const float* xp = x + (size_t)(t0 + c) * HIDDEN + k0 + g * 8;
    const unsigned short* bh = whb + (size_t)c * HIDDEN + k0 + g * 8;
    const unsigned short* bl = wlb + (size_t)c * HIDDEN + k0 + g * 8;

    // software pipeline: A double-buffered in regs
    float4 a0A = *(const float4*)(xp);
    float4 a1A = *(const float4*)(xp + 4);
    float4 a0B, a1B;
#pragma unroll
    for (int ck = 0; ck < NCHUNK; ck += 2) {
        a0B = *(const float4*)(xp + (ck + 1) * 32);
        a1B = *(const float4*)(xp + (ck + 1) * 32 + 4);
        do_chunk(a0A, a1A, bh, bl, ck * 32, acc);
        if (ck + 2 < NCHUNK) {
            a0A = *(const float4*)(xp + (ck + 2) * 32);
            a1A = *(const float4*)(xp + (ck + 2) * 32 + 4);
        }
        do_chunk(a0B, a1B, bh, bl, (ck + 1) * 32, acc);
    }

    // ---- partials to LDS: C layout col=lane&15, row=(lane>>4)*4+reg ----
#pragma unroll
    for (int n = 0; n < 4; ++n)
#pragma unroll
        for (int r = 0; r < 4; ++r)
            lds[w][g * 4 + r][n * 16 + c] = acc[n][r];
    __syncthreads();

    // ---- cross-wave reduce: 1024 cells, 2 per thread ----
#pragma unroll
    for (int i = 0; i < 2; ++i) {
        const int cell = tid * 2 + i;
        const int t = cell >> 6, e = cell & 63;
        float s = lds[0][t][e];
#pragma unroll
        for (int sp = 1; sp < SPLIT; ++sp) s += lds[sp][t][e];
        lds[0][t][e] = s;
    }
    __syncthreads();

    // ---- softmax + top-9 + outputs: waves 0..3, 4 tokens each (16-lane grp) ----
    if (tid < 256) {
        const int t = w * 4 + g;
        float v[4];
#pragma unroll
        for (int s = 0; s < 4; ++s) v[s] = lds[0][t][s * 16 + c];

        float mx = fmaxf(fmaxf(v[0], v[1]), fmaxf(v[2], v[3]));
#pragma unroll
        for (int off = 1; off < 16; off <<= 1) mx = fmaxf(mx, __shfl_xor(mx, off));
        float sum = 0.f;
#pragma unroll
        for (int s = 0; s < 4; ++s) { v[s] = __expf(v[s] - mx); sum += v[s]; }
#pragma unroll
        for (int off = 1; off < 16; off <<= 1) sum += __shfl_xor(sum, off);
        const float inv = 1.0f / sum;
#pragma unroll
        for (int s = 0; s < 4; ++s) v[s] *= inv;

        float cur[4] = {v[0], v[1], v[2], v[3]};
        unsigned selmask = 0;
        float v8 = 0.f, v9 = 0.f;
#pragma unroll
        for (int it = 0; it < 9; ++it) {
            float bv = cur[0];
            int be = c;
#pragma unroll
            for (int s = 1; s < 4; ++s)
                if (cur[s] > bv) { bv = cur[s]; be = s * 16 + c; }
#pragma unroll
            for (int off = 1; off < 16; off <<= 1) {
                const float ov = __shfl_xor(bv, off);
                const int oe = __shfl_xor(be, off);
                if (ov > bv || (ov == bv && oe < be)) { bv = ov; be = oe; }
            }
            if (it < 8) {
                if ((be & 15) == c) { cur[be >> 4] = -1.f; selmask |= 1u << (be >> 4); }
                if (it == 7) v8 = bv;
            } else {
                v9 = bv;
            }
        }
        // near-tie rescue flag: covers any selection ambiguity >10x our error
        if (c == 0 && (v8 - v9) < v8 * 1e-3f) {
            const int idx = atomicAdd(flag_cnt, 1);
            flag_list[idx] = t0 + t;
        }
#pragma unroll
        for (int s = 0; s < 4; ++s) {
            const bool sel = (selmask >> s) & 1u;
            out[(size_t)(t0 + t) * 64 + s * 16 + c] = sel ? v[s] : 0.f;
            out[(size_t)TOKENS * 64 + (size_t)(t0 + t) * 64 + s * 16 + c] = sel ? 1.f : 0.f;
        }
    }
}

// ---------------------------------------------------------------------------
// Rescue: exact f32 recompute of flagged tokens (near-tie at rank 8/9).
// ---------------------------------------------------------------------------
__global__ __launch_bounds__(256)
void router_rescue(const float* __restrict__ x, const float* __restrict__ wgt,
                   float* __restrict__ out, const int* __restrict__ cnt,
                   const int* __restrict__ list) {
    __shared__ float xrow[HIDDEN];        // 16 KB
    __shared__ float lg[EXPERTS];
    const int tid = threadIdx.x;
    const int w = tid >> 6, lane = tid & 63;
    const int n = cnt[0];
    for (int i = blockIdx.x; i < n; i += 256) {
        const int t = list[i];
        __syncthreads();
        for (int j = tid; j < HIDDEN / 4; j += 256)
            ((float4*)xrow)[j] = ((const float4*)(x + (size_t)t * HIDDEN))[j];
        __syncthreads();
#pragma unroll 2
        for (int ei = 0; ei < 16; ++ei) {
            const int e = w * 16 + ei;
            const float* wr = wgt + (size_t)e * HIDDEN;
            float a = 0.f;
            for (int kk = 0; kk < HIDDEN; kk += 256) {
                const float4 xv = *(const float4*)(xrow + kk + lane * 4);
                const float4 wv = *(const float4*)(wr + kk + lane * 4);
                a = fmaf(xv.x, wv.x, a); a = fmaf(xv.y, wv.y, a);
                a = fmaf(xv.z, wv.z, a); a = fmaf(xv.w, wv.w, a);
            }
#pragma unroll
            for (int off = 32; off >= 1; off >>= 1) a += __shfl_xor(a, off);
            if (lane == 0) lg[e] = a;
        }
        __syncthreads();
        if (w == 0) {
            const float logit = lg[lane];
            float m = logit;
#pragma unroll
            for (int off = 32; off >= 1; off >>= 1) m = fmaxf(m, __shfl_xor(m, off));
            const float ex = __expf(logit - m);
            float sum = ex;
#pragma unroll
            for (int off = 32; off >= 1; off >>= 1) sum += __shfl_xor(sum, off);
            const float score = ex / sum;
            float v = score;
            bool sel = false;
#pragma unroll
            for (int it = 0; it < 8; ++it) {
                float bv = v; int bi = lane;
#pragma unroll
                for (int off = 32; off >= 1; off >>= 1) {
                    const float ov = __shfl_xor(bv, off);
                    const int oi = __shfl_xor(bi, off);
                    if (ov > bv || (ov == bv && oi < bi)) { bv = ov; bi = oi; }
                }
                if (lane == bi) { sel = true; v = -1.f; }
            }
            out[(size_t)t * 64 + lane] = sel ? score : 0.f;
            out[(size_t)TOKENS * 64 + (size_t)t * 64 + lane] = sel ? 1.f : 0.f;
        }
        __syncthreads();
    }
}

// ---------------------------------------------------------------------------
extern "C" void kernel_launch(void* const* d_in, const int* in_sizes, int n_in,
                              void* d_out, int out_size, void* d_ws, size_t ws_size,
                              hipStream_t stream) {
    (void)in_sizes; (void)n_in; (void)out_size; (void)ws_size;
    const float* x = (const float*)d_in[0];       // [8192][4096] f32
    const float* w = (const float*)d_in[1];       // [64][4096] f32
    float* out = (float*)d_out;

    unsigned short* whb = (unsigned short*)d_ws;                        // 512 KB
    unsigned short* wlb = (unsigned short*)((char*)d_ws + (512 << 10)); // 512 KB
    int* flag_cnt = (int*)((char*)d_ws + (1 << 20));
    int* flag_list = (int*)((char*)d_ws + (1 << 20) + 64);

    hipMemsetAsync(flag_cnt, 0, sizeof(int), stream);
    prep_w<<<(EXPERTS * HIDDEN) / 256, 256, 0, stream>>>(w, whb, wlb);
    router_main<<<TOKENS / 16, 512, 0, stream>>>(x, whb, wlb, out,
                                                 flag_cnt, flag_list);
    router_rescue<<<256, 256, 0, stream>>>(x, w, out, flag_cnt, flag_list);
}

// Round 7
// 108.362 us; speedup vs baseline: 1.3682x; 1.3682x over previous
//
#include <hip/hip_runtime.h>

#define TOKENS 8192
#define EXPERTS 64
#define HIDDEN 4096
#define SPLIT 8                  // K-segments (grid dimension)
#define KSEG (HIDDEN / SPLIT)    // 512 k per block
#define NS (KSEG / 32)           // 16 K-steps of 32
#define BM 128                   // tokens per block
#define LDA 40                   // LDS row stride in ushorts (80B: 2-way max alias)

typedef __attribute__((ext_vector_type(8))) short bf16x8;
typedef __attribute__((ext_vector_type(4))) float f32x4;

__device__ __forceinline__ unsigned short bf16_rne(float f) {
    unsigned u = __float_as_uint(f);
    return (unsigned short)((u + 0x7FFFu + ((u >> 16) & 1u)) >> 16);
}

// split float4 -> hi (RNE) + lo (trunc) bf16 quads
__device__ __forceinline__ void split4(const float4& f, uint2& h, uint2& l) {
    unsigned short hs[4], ls[4];
    const float* fp = (const float*)&f;
#pragma unroll
    for (int j = 0; j < 4; ++j) {
        const unsigned u = __float_as_uint(fp[j]);
        const unsigned hb = (u + 0x7FFFu + ((u >> 16) & 1u)) >> 16;
        const float hf = __uint_as_float(hb << 16);
        hs[j] = (unsigned short)hb;
        ls[j] = (unsigned short)(__float_as_uint(fp[j] - hf) >> 16);
    }
    h = *(const uint2*)hs;
    l = *(const uint2*)ls;
}

// ---------------------------------------------------------------------------
// Kernel A: split w (f32) into hi/lo bf16 planes, row-major [e][k]
// ---------------------------------------------------------------------------
__global__ void prep_w(const float* __restrict__ w,
                       unsigned short* __restrict__ wh,
                       unsigned short* __restrict__ wl) {
    const int i = blockIdx.x * 256 + threadIdx.x;
    const float f = w[i];
    const unsigned short hb = bf16_rne(f);
    const float hf = __uint_as_float(((unsigned)hb) << 16);
    wh[i] = hb;
    wl[i] = bf16_rne(f - hf);
}

// ---------------------------------------------------------------------------
// Kernel B: canonical LDS-staged GEMM partial.
// Grid = 64 token-groups x 8 K-segments. Block 256 thr / 4 waves.
// Tile M=128 x N=64 x K=512, K_STEP=32. A,B staged as bf16 hi/lo in LDS
// (double-buffered); one barrier per K-step; loads issued 2 steps ahead.
// Wave w owns M-frags {2w, 2w+1} x all 4 N-frags; 3-pass bf16-split MFMA.
// ---------------------------------------------------------------------------
__global__ __launch_bounds__(256)
void gemm_partial(const float* __restrict__ x,
                  const unsigned short* __restrict__ whb,
                  const unsigned short* __restrict__ wlb,
                  float* __restrict__ part) {
    __shared__ unsigned short As[2][2][BM][LDA];       // 40960 B
    __shared__ unsigned short Bs[2][2][EXPERTS][LDA];  // 20480 B
    const int tid = threadIdx.x;
    const int w = tid >> 6;
    const int lane = tid & 63;
    const int g = lane >> 4;              // k-octet
    const int c = lane & 15;              // row (A) / col (B) within frag
    const int t0 = (blockIdx.x / SPLIT) * BM;
    const int ks0 = blockIdx.x % SPLIT;
    const int k0 = ks0 * KSEG;

    // staging geometry
    const int arow = tid >> 3;            // 0..31 (4 passes of 32 rows)
    const int acol = (tid & 7) * 4;       // f32 quad within 32-k step
    const int brow = tid >> 2;            // 0..63 expert row
    const int bcol = (tid & 3) * 8;       // ushort octet within step

    const float* xb = x + (size_t)(t0 + arow) * HIDDEN + k0 + acol;
    const unsigned short* bhb = whb + (size_t)brow * HIDDEN + k0 + bcol;
    const unsigned short* blb = wlb + (size_t)brow * HIDDEN + k0 + bcol;

    float4 ra[4];
    uint4 rbh, rbl;

#define LOADSTEP(ks)                                                     \
    do {                                                                 \
        const int _o = (ks) * 32;                                        \
        ra[0] = *(const float4*)(xb + _o);                               \
        ra[1] = *(const float4*)(xb + (size_t)32 * HIDDEN + _o);         \
        ra[2] = *(const float4*)(xb + (size_t)64 * HIDDEN + _o);         \
        ra[3] = *(const float4*)(xb + (size_t)96 * HIDDEN + _o);         \
        rbh = *(const uint4*)(bhb + _o);                                 \
        rbl = *(const uint4*)(blb + _o);                                 \
    } while (0)

#define WRITESTEP(buf)                                                   \
    do {                                                                 \
        _Pragma("unroll")                                                \
        for (int p = 0; p < 4; ++p) {                                    \
            uint2 h, l;                                                  \
            split4(ra[p], h, l);                                         \
            *(uint2*)&As[buf][0][p * 32 + arow][acol] = h;               \
            *(uint2*)&As[buf][1][p * 32 + arow][acol] = l;               \
        }                                                                \
        *(uint4*)&Bs[buf][0][brow][bcol] = rbh;                          \
        *(uint4*)&Bs[buf][1][brow][bcol] = rbl;                          \
    } while (0)

    f32x4 acc[2][4];
#pragma unroll
    for (int m = 0; m < 2; ++m)
#pragma unroll
        for (int n = 0; n < 4; ++n) acc[m][n] = (f32x4)0.0f;

    LOADSTEP(0);
    WRITESTEP(0);
    LOADSTEP(1);
    __syncthreads();

#pragma unroll 2
    for (int ks = 0; ks < NS; ++ks) {
        const int cur = ks & 1;
        if (ks + 1 < NS) {
            WRITESTEP(1 - cur);           // waits on step ks+1 loads (issued 1 step ago)
            if (ks + 2 < NS) LOADSTEP(ks + 2);
        }
        // compute step ks from buf[cur]
#pragma unroll
        for (int m = 0; m < 2; ++m) {
            const int row = (w * 2 + m) * 16 + c;
            const bf16x8 ah = *(const bf16x8*)&As[cur][0][row][g * 8];
            const bf16x8 al = *(const bf16x8*)&As[cur][1][row][g * 8];
#pragma unroll
            for (int n = 0; n < 4; ++n) {
                const bf16x8 bh = *(const bf16x8*)&Bs[cur][0][n * 16 + c][g * 8];
                const bf16x8 bl = *(const bf16x8*)&Bs[cur][1][n * 16 + c][g * 8];
                acc[m][n] = __builtin_amdgcn_mfma_f32_16x16x32_bf16(ah, bh, acc[m][n], 0, 0, 0);
                acc[m][n] = __builtin_amdgcn_mfma_f32_16x16x32_bf16(ah, bl, acc[m][n], 0, 0, 0);
                acc[m][n] = __builtin_amdgcn_mfma_f32_16x16x32_bf16(al, bh, acc[m][n], 0, 0, 0);
            }
        }
        __syncthreads();
    }
#undef LOADSTEP
#undef WRITESTEP

    // partial write: C layout col=lane&15, row=(lane>>4)*4+r
    float* pb = part + ((size_t)ks0 * TOKENS + t0) * EXPERTS;
#pragma unroll
    for (int m = 0; m < 2; ++m)
#pragma unroll
        for (int n = 0; n < 4; ++n)
#pragma unroll
            for (int r = 0; r < 4; ++r)
                pb[(size_t)((w * 2 + m) * 16 + g * 4 + r) * EXPERTS + n * 16 + c] =
                    acc[m][n][r];
}

// ---------------------------------------------------------------------------
// Kernel C: reduce partials -> softmax -> top-9 -> outputs + near-tie flags.
// One wave per token; lane = expert. Tie-break: lower index (lax.top_k).
// ---------------------------------------------------------------------------
__global__ __launch_bounds__(256)
void reduce_topk_kernel(const float* __restrict__ part,
                        float* __restrict__ out,
                        int* __restrict__ flag_cnt,
                        int* __restrict__ flag_list) {
    const int wid = threadIdx.x >> 6;
    const int lane = threadIdx.x & 63;
    const int t = blockIdx.x * 4 + wid;

    float logit = 0.0f;
#pragma unroll
    for (int s = 0; s < SPLIT; ++s)
        logit += part[((size_t)s * TOKENS + t) * EXPERTS + lane];

    float m = logit;
#pragma unroll
    for (int off = 32; off >= 1; off >>= 1) m = fmaxf(m, __shfl_xor(m, off, 64));
    const float ex = __expf(logit - m);
    float sum = ex;
#pragma unroll
    for (int off = 32; off >= 1; off >>= 1) sum += __shfl_xor(sum, off, 64);
    const float score = ex / sum;

    float v = score;
    bool sel = false;
    float v8 = 0.f, v9 = 0.f;
#pragma unroll
    for (int it = 0; it < 9; ++it) {
        float bv = v;
        int bi = lane;
#pragma unroll
        for (int off = 32; off >= 1; off >>= 1) {
            const float ov = __shfl_xor(bv, off, 64);
            const int oi = __shfl_xor(bi, off, 64);
            if (ov > bv || (ov == bv && oi < bi)) { bv = ov; bi = oi; }
        }
        if (it < 8) {
            if (lane == bi) { sel = true; v = -1.0f; }
            if (it == 7) v8 = bv;
        } else {
            v9 = bv;
        }
    }
    if (lane == 0 && (v8 - v9) < v8 * 1e-3f) {
        const int idx = atomicAdd(flag_cnt, 1);
        flag_list[idx] = t;
    }
    out[(size_t)t * EXPERTS + lane] = sel ? score : 0.f;
    out[(size_t)TOKENS * EXPERTS + (size_t)t * EXPERTS + lane] = sel ? 1.f : 0.f;
}

// ---------------------------------------------------------------------------
// Rescue: exact f32 recompute of flagged tokens (near-tie at rank 8/9).
// ---------------------------------------------------------------------------
__global__ __launch_bounds__(256)
void router_rescue(const float* __restrict__ x, const float* __restrict__ wgt,
                   float* __restrict__ out, const int* __restrict__ cnt,
                   const int* __restrict__ list) {
    __shared__ float xrow[HIDDEN];
    __shared__ float lg[EXPERTS];
    const int tid = threadIdx.x;
    const int w = tid >> 6, lane = tid & 63;
    const int n = cnt[0];
    for (int i = blockIdx.x; i < n; i += 256) {
        const int t = list[i];
        __syncthreads();
        for (int j = tid; j < HIDDEN / 4; j += 256)
            ((float4*)xrow)[j] = ((const float4*)(x + (size_t)t * HIDDEN))[j];
        __syncthreads();
#pragma unroll 2
        for (int ei = 0; ei < 16; ++ei) {
            const int e = w * 16 + ei;
            const float* wr = wgt + (size_t)e * HIDDEN;
            float a = 0.f;
            for (int kk = 0; kk < HIDDEN; kk += 256) {
                const float4 xv = *(const float4*)(xrow + kk + lane * 4);
                const float4 wv = *(const float4*)(wr + kk + lane * 4);
                a = fmaf(xv.x, wv.x, a); a = fmaf(xv.y, wv.y, a);
                a = fmaf(xv.z, wv.z, a); a = fmaf(xv.w, wv.w, a);
            }
#pragma unroll
            for (int off = 32; off >= 1; off >>= 1) a += __shfl_xor(a, off, 64);
            if (lane == 0) lg[e] = a;
        }
        __syncthreads();
        if (w == 0) {
            const float logit = lg[lane];
            float m = logit;
#pragma unroll
            for (int off = 32; off >= 1; off >>= 1) m = fmaxf(m, __shfl_xor(m, off, 64));
            const float ex = __expf(logit - m);
            float sum = ex;
#pragma unroll
            for (int off = 32; off >= 1; off >>= 1) sum += __shfl_xor(sum, off, 64);
            const float score = ex / sum;
            float v = score;
            bool sel = false;
#pragma unroll
            for (int it = 0; it < 8; ++it) {
                float bv = v; int bi = lane;
#pragma unroll
                for (int off = 32; off >= 1; off >>= 1) {
                    const float ov = __shfl_xor(bv, off, 64);
                    const int oi = __shfl_xor(bi, off, 64);
                    if (ov > bv || (ov == bv && oi < bi)) { bv = ov; bi = oi; }
                }
                if (lane == bi) { sel = true; v = -1.f; }
            }
            out[(size_t)t * EXPERTS + lane] = sel ? score : 0.f;
            out[(size_t)TOKENS * EXPERTS + (size_t)t * EXPERTS + lane] = sel ? 1.f : 0.f;
        }
        __syncthreads();
    }
}

// ---------------------------------------------------------------------------
extern "C" void kernel_launch(void* const* d_in, const int* in_sizes, int n_in,
                              void* d_out, int out_size, void* d_ws, size_t ws_size,
                              hipStream_t stream) {
    (void)in_sizes; (void)n_in; (void)out_size; (void)ws_size;
    const float* x = (const float*)d_in[0];       // [8192][4096] f32
    const float* w = (const float*)d_in[1];       // [64][4096] f32
    float* out = (float*)d_out;

    unsigned short* whb = (unsigned short*)d_ws;                        // 512 KB
    unsigned short* wlb = (unsigned short*)((char*)d_ws + (512 << 10)); // 512 KB
    float* part = (float*)((char*)d_ws + (1 << 20));                    // 16 MB
    int* flag_cnt = (int*)((char*)d_ws + (17 << 20));
    int* flag_list = (int*)((char*)d_ws + (17 << 20) + 64);

    hipMemsetAsync(flag_cnt, 0, sizeof(int), stream);
    prep_w<<<(EXPERTS * HIDDEN) / 256, 256, 0, stream>>>(w, whb, wlb);
    gemm_partial<<<(TOKENS / BM) * SPLIT, 256, 0, stream>>>(x, whb, wlb, part);
    reduce_topk_kernel<<<TOKENS / 4, 256, 0, stream>>>(part, out, flag_cnt, flag_list);
    router_rescue<<<256, 256, 0, stream>>>(x, w, out, flag_cnt, flag_list);
}